// Round 1
// baseline (305.731 us; speedup 1.0000x reference)
//
#include <hip/hip_runtime.h>

// ---- problem constants ----
#define BB 8
#define NN 20000
#define KK 9
#define CC 64
#define KC 576                 // KK*CC
#define ROWS (BB*NN)           // 160000

// ---- workspace layout (in ushort elements for the bf16 area) ----
#define WST_ELE   (18*64*32)          // conv_w chunks: 36864 bf16
#define WST2_ELE  (2*64*32)           // mlp_w chunks : 4096 bf16
#define ADJ_ELE   (NN*88)             // adj rows padded to 88 bf16: 1,760,000
#define WST_OFF   0
#define WST2_OFF  (WST_ELE)
#define ADJ_OFF   (WST_ELE + WST2_ELE)          // byte offset 81920 (16B aligned)
#define ZERO_EOFF (ADJ_OFF + ADJ_ELE)           // byte offset 3,601,920 (16B aligned)
#define PREP_THREADS (ADJ_ELE)                  // largest job

typedef __bf16 bf16x8 __attribute__((ext_vector_type(8)));
typedef float  f32x4  __attribute__((ext_vector_type(4)));
typedef unsigned short u16x8 __attribute__((ext_vector_type(8)));

__device__ __forceinline__ unsigned short f2bf(float f) {
    unsigned u = __builtin_bit_cast(unsigned, f);
    u += 0x7FFFu + ((u >> 16) & 1u);          // round-to-nearest-even
    return (unsigned short)(u >> 16);
}
__device__ __forceinline__ float bfhi2f(unsigned w) {   // upper bf16 of dword
    return __builtin_bit_cast(float, w & 0xFFFF0000u);
}
__device__ __forceinline__ float bflo2f(unsigned w) {   // lower bf16 of dword
    return __builtin_bit_cast(float, w << 16);
}
__device__ __forceinline__ float elu_f(float v) {
    return v > 0.0f ? v : (__expf(v) - 1.0f);
}

// ---------------------------------------------------------------------------
// Prep: repack conv_w / mlp_w into MFMA-chunk order (bf16), adj rows into
// padded bf16 rows, and zero a 256B "dead neighbor" region.
// ---------------------------------------------------------------------------
__global__ void __launch_bounds__(256) paiconv_prep(
        const float* __restrict__ adj,     // [NN][9][9]
        const float* __restrict__ conv_w,  // [64][576]
        const float* __restrict__ mlp_w,   // [64][64]
        unsigned short* __restrict__ ws16) {
    int tid = blockIdx.x * 256 + threadIdx.x;

    if (tid < WST_ELE) {   // Wst[mch][o][kk] = conv_w[o][t*64 + c*32 + kk], mch=c*9+t
        int kk = tid & 31, o = (tid >> 5) & 63, mch = tid >> 11;
        int c = mch / 9, t = mch - 9 * c;
        ws16[WST_OFF + tid] = f2bf(conv_w[o * KC + t * 64 + c * 32 + kk]);
    }
    if (tid < WST2_ELE) {  // Wst2[c2][o][kk] = mlp_w[o][c2*32 + kk]
        int kk = tid & 31, o = (tid >> 5) & 63, c2 = tid >> 11;
        ws16[WST2_OFF + tid] = f2bf(mlp_w[o * 64 + c2 * 32 + kk]);
    }
    if (tid < 128) {       // 256B zero region (read when neighbor == NN-1)
        ((unsigned short*)(ws16 + ZERO_EOFF))[tid] = 0;
    }
    if (tid < ADJ_ELE) {   // adj rows, stride padded 81 -> 88 bf16 (176B, 16B aligned)
        int n = tid / 88, j = tid - 88 * n;
        ws16[ADJ_OFF + tid] = (j < 81) ? f2bf(adj[n * 81 + j]) : (unsigned short)0;
    }
}

// ---------------------------------------------------------------------------
// Main fused kernel: gather + adj-mix + ELU + conv GEMM (MFMA bf16) + ELU +
// mask + residual GEMM (MFMA bf16) + biases.  1 wave = 16 rows, block = 64.
// ---------------------------------------------------------------------------
__global__ void __launch_bounds__(256, 2) paiconv_main(
        const float* __restrict__ x,        // [BB*NN][64]
        const int*   __restrict__ nidx,     // [BB*NN][9]
        const float* __restrict__ conv_b,   // [64]
        const float* __restrict__ mlp_b,    // [64]
        const unsigned short* __restrict__ ws16,
        float* __restrict__ out) {          // [BB*NN][64]
    const int tx   = threadIdx.x;
    const int lane = tx & 63;
    const int l15  = lane & 15;
    const int q    = lane >> 4;
    const int wave = __builtin_amdgcn_readfirstlane(tx >> 6);
    const int rowbase = blockIdx.x * 64 + wave * 16;
    const int b   = rowbase / NN;                 // uniform per wave
    const int n0  = rowbase - b * NN;             // uniform per wave
    const int myrow = rowbase + l15;              // this lane's point row
    const int myn   = n0 + l15;

    const unsigned short* Wst  = ws16 + WST_OFF;
    const unsigned short* Wst2 = ws16 + WST2_OFF;
    const unsigned short* Adj  = ws16 + ADJ_OFF;
    const float* Z = (const float*)(ws16 + ZERO_EOFF);

    // ---- neighbor indices for my row; select zero-region for idx == NN-1 ----
    const float* bp[KK];
    #pragma unroll
    for (int k = 0; k < KK; ++k) {
        int idx = nidx[myrow * KK + k];
        const float* p = x + (size_t)(b * NN + idx) * 64;
        bp[k] = (idx == NN - 1) ? Z : p;
    }

    // ---- adj row (81 bf16, padded 88) -> registers: 11 aligned uint4 loads ----
    unsigned adjw[44];
    {
        const uint4* ap = (const uint4*)(Adj + (size_t)myn * 88);
        #pragma unroll
        for (int u = 0; u < 11; ++u) {
            uint4 w = ap[u];
            adjw[4 * u + 0] = w.x; adjw[4 * u + 1] = w.y;
            adjw[4 * u + 2] = w.z; adjw[4 * u + 3] = w.w;
        }
    }

    f32x4 acc[4];    // conv accumulators, one per o-tile of 16
    f32x4 acc2[4];   // residual accumulators
    #pragma unroll
    for (int ot = 0; ot < 4; ++ot) { acc[ot] = (f32x4)0.0f; acc2[ot] = (f32x4)0.0f; }

    // ---- main: 2 f-halves (c) x 9 neighbor slots (t), K-chunk = 32 ----
    #pragma unroll 1
    for (int c = 0; c < 2; ++c) {
        // gather this lane's row fragment for all 9 neighbors: f = c*32 + q*8 + i
        float v[KK][8];
        #pragma unroll
        for (int k = 0; k < KK; ++k) {
            const float* p = bp[k] + c * 32 + q * 8;
            f32x4 lo = *(const f32x4*)p;
            f32x4 hi = *(const f32x4*)(p + 4);
            #pragma unroll
            for (int i = 0; i < 4; ++i) { v[k][i] = lo[i]; v[k][4 + i] = hi[i]; }
        }
        #pragma unroll
        for (int t = 0; t < KK; ++t) {
            float m[8] = {0.f,0.f,0.f,0.f,0.f,0.f,0.f,0.f};
            #pragma unroll
            for (int k = 0; k < KK; ++k) {
                const int j = k * 9 + t;                     // compile-time
                unsigned w = adjw[j >> 1];
                float a = (j & 1) ? bfhi2f(w) : bflo2f(w);
                #pragma unroll
                for (int i = 0; i < 8; ++i) m[i] = __builtin_fmaf(a, v[k][i], m[i]);
            }
            u16x8 pk;
            #pragma unroll
            for (int i = 0; i < 8; ++i) pk[i] = f2bf(elu_f(m[i]));
            bf16x8 afrag = __builtin_bit_cast(bf16x8, pk);
            const int mch = c * 9 + t;
            #pragma unroll
            for (int ot = 0; ot < 4; ++ot) {
                const u16x8* wp = (const u16x8*)(Wst + mch * 2048 + (ot * 16 + l15) * 32 + q * 8);
                bf16x8 bfrag = __builtin_bit_cast(bf16x8, *wp);
                acc[ot] = __builtin_amdgcn_mfma_f32_16x16x32_bf16(afrag, bfrag, acc[ot], 0, 0, 0);
            }
        }
    }

    // ---- residual GEMM: x(masked) @ mlp_w^T ----
    #pragma unroll
    for (int c2 = 0; c2 < 2; ++c2) {
        const float* ps = x + (size_t)myrow * 64 + c2 * 32 + q * 8;
        f32x4 lo = *(const f32x4*)ps;
        f32x4 hi = *(const f32x4*)(ps + 4);
        const bool dead = (myn == NN - 1);     // zero-padded point
        u16x8 pk;
        #pragma unroll
        for (int i = 0; i < 8; ++i) {
            float xv = (i < 4) ? lo[i] : hi[i - 4];
            pk[i] = f2bf(dead ? 0.0f : xv);
        }
        bf16x8 a2 = __builtin_bit_cast(bf16x8, pk);
        #pragma unroll
        for (int ot = 0; ot < 4; ++ot) {
            const u16x8* wp = (const u16x8*)(Wst2 + c2 * 2048 + (ot * 16 + l15) * 32 + q * 8);
            bf16x8 b2 = __builtin_bit_cast(bf16x8, *wp);
            acc2[ot] = __builtin_amdgcn_mfma_f32_16x16x32_bf16(a2, b2, acc2[ot], 0, 0, 0);
        }
    }

    // ---- epilogue: elu(conv + conv_b)*mask + res + mlp_b ----
    #pragma unroll
    for (int ot = 0; ot < 4; ++ot) {
        const int o = ot * 16 + l15;
        const float cb = conv_b[o];
        const float mb = mlp_b[o];
        #pragma unroll
        for (int i = 0; i < 4; ++i) {
            const int rr = 4 * q + i;                    // C/D: row = 4*(lane>>4)+reg
            const int nrow = n0 + rr;
            float f = elu_f(acc[ot][i] + cb);
            if (nrow == NN - 1) f = 0.0f;                // output mask
            f += acc2[ot][i] + mb;
            out[(size_t)(rowbase + rr) * 64 + o] = f;
        }
    }
}

extern "C" void kernel_launch(void* const* d_in, const int* in_sizes, int n_in,
                              void* d_out, int out_size, void* d_ws, size_t ws_size,
                              hipStream_t stream) {
    const float* x      = (const float*)d_in[0];
    const int*   nidx   = (const int*)  d_in[1];
    const float* adj    = (const float*)d_in[2];
    const float* conv_w = (const float*)d_in[3];
    const float* conv_b = (const float*)d_in[4];
    const float* mlp_w  = (const float*)d_in[5];
    const float* mlp_b  = (const float*)d_in[6];
    unsigned short* ws16 = (unsigned short*)d_ws;
    float* out = (float*)d_out;

    const int prep_blocks = (PREP_THREADS + 255) / 256;   // 6875
    paiconv_prep<<<prep_blocks, 256, 0, stream>>>(adj, conv_w, mlp_w, ws16);

    const int main_blocks = ROWS / 64;                    // 2500
    paiconv_main<<<main_blocks, 256, 0, stream>>>(x, nidx, conv_b, mlp_b, ws16, out);
}

// Round 10
// 302.790 us; speedup vs baseline: 1.0097x; 1.0097x over previous
//
#include <hip/hip_runtime.h>

// ---- problem constants ----
#define BB 8
#define NN 20000
#define KK 9
#define KC 576                 // KK*64
#define ROWS (BB*NN)           // 160000

// ---- workspace layout (ushort elements) ----
#define WST_ELE   36864                 // conv_w chunks [18][64][32]
#define WST2_ELE  4096                  // mlp_w chunks  [2][64][32]
#define ADJ_ELE   (NN*88)               // adj rows padded 81->88 bf16
#define XB_ELE    (ROWS*64)             // x in bf16, row NN-1 per batch zeroed
#define WST_OFF   0
#define WST2_OFF  36864
#define ADJ_OFF   40960                 // byte 81,920 (16B aligned)
#define XB_OFF    (ADJ_OFF + ADJ_ELE)   // elem 1,800,960; byte 3,601,920 (16B aligned)
// total ws use: 12,040,960 ushort = 24.1 MB

typedef __bf16 bf16x8 __attribute__((ext_vector_type(8)));
typedef float  f32x4  __attribute__((ext_vector_type(4)));
typedef unsigned short u16x8 __attribute__((ext_vector_type(8)));
typedef unsigned u32x4 __attribute__((ext_vector_type(4)));

__device__ __forceinline__ unsigned short f2bf(float f) {
    unsigned u = __builtin_bit_cast(unsigned, f);
    u += 0x7FFFu + ((u >> 16) & 1u);          // RNE
    return (unsigned short)(u >> 16);
}
__device__ __forceinline__ float bfhi2f(unsigned w) { return __builtin_bit_cast(float, w & 0xFFFF0000u); }
__device__ __forceinline__ float bflo2f(unsigned w) { return __builtin_bit_cast(float, w << 16); }
__device__ __forceinline__ float elu_f(float v) { return v > 0.0f ? v : (__expf(v) - 1.0f); }

// ---------------------------------------------------------------------------
// Prep: x -> bf16 (row NN-1 per batch zeroed), adj -> bf16 padded rows,
// conv_w / mlp_w -> MFMA chunk order.
// ---------------------------------------------------------------------------
__global__ void __launch_bounds__(256) paiconv_prep(
        const float* __restrict__ x,       // [ROWS][64]
        const float* __restrict__ adj,     // [NN][81]
        const float* __restrict__ conv_w,  // [64][576]
        const float* __restrict__ mlp_w,   // [64][64]
        unsigned short* __restrict__ ws16) {
    const int tid = blockIdx.x * 256 + threadIdx.x;

    if (tid < XB_ELE / 8) {                    // 1,280,000 threads: 8 elems each
        const int e = tid * 8;
        const int r = e >> 6;                  // global row
        const int n = r % NN;                  // within-batch row
        u16x8 pk;
        if (n == NN - 1) {
            #pragma unroll
            for (int i = 0; i < 8; ++i) pk[i] = 0;   // pre-masked row
        } else {
            f32x4 lo = *(const f32x4*)(x + e);
            f32x4 hi = *(const f32x4*)(x + e + 4);
            #pragma unroll
            for (int i = 0; i < 4; ++i) { pk[i] = f2bf(lo[i]); pk[4 + i] = f2bf(hi[i]); }
        }
        *(u16x8*)(ws16 + XB_OFF + e) = pk;
    }
    if (tid < NN * 11) {                       // adj: 11 8-elem chunks per row
        const int n = tid / 11;
        const int j = (tid - n * 11) * 8;
        u16x8 pk;
        #pragma unroll
        for (int m = 0; m < 8; ++m) {
            const int jj = j + m;
            pk[m] = (jj < 81) ? f2bf(adj[n * 81 + jj]) : (unsigned short)0;
        }
        *(u16x8*)(ws16 + ADJ_OFF + n * 88 + j) = pk;
    }
    if (tid < WST_ELE) {   // Wst[mch][o][kk] = conv_w[o][t*64 + c*32 + kk], mch=c*9+t
        const int kk = tid & 31, o = (tid >> 5) & 63, mch = tid >> 11;
        const int c = mch / 9, t = mch - 9 * c;
        ws16[WST_OFF + tid] = f2bf(conv_w[o * KC + t * 64 + c * 32 + kk]);
    }
    if (tid < WST2_ELE) {  // Wst2[c2][o][kk] = mlp_w[o][c2*32 + kk]
        const int kk = tid & 31, o = (tid >> 5) & 63, c2 = tid >> 11;
        ws16[WST2_OFF + tid] = f2bf(mlp_w[o * 64 + c2 * 32 + kk]);
    }
}

// ---------------------------------------------------------------------------
// Main fused kernel. Grid = 8 batches x 313 chunks, batch = blockIdx & 7 so
// each batch's blocks pin to one XCD (L2-resident 2.56 MB bf16 x-slice).
// 1 wave = 16 rows; block = 4 waves; no __syncthreads.
// ---------------------------------------------------------------------------
__global__ void __launch_bounds__(256, 2) paiconv_main(
        const int*   __restrict__ nidx,     // [ROWS][9]
        const float* __restrict__ conv_b,   // [64]
        const float* __restrict__ mlp_b,    // [64]
        const unsigned short* __restrict__ ws16,
        float* __restrict__ out) {          // [ROWS][64]
    __shared__ float sm[4][16][68];

    const int tx   = threadIdx.x;
    const int lane = tx & 63;
    const int l15  = lane & 15;
    const int q    = lane >> 4;
    const int wave = tx >> 6;
    const int batch = blockIdx.x & 7;          // XCD pin
    const int chunk = blockIdx.x >> 3;
    const int n0    = chunk * 64 + wave * 16;  // within-batch base row of wave
    if (n0 >= NN) return;                      // tail (chunk 312, waves 2,3)
    const int rowbase = batch * NN + n0;
    const int myrow   = rowbase + l15;
    const int myn     = n0 + l15;

    const unsigned short* Wst  = ws16 + WST_OFF;
    const unsigned short* Wst2 = ws16 + WST2_OFF;
    const unsigned short* Adj  = ws16 + ADJ_OFF;
    const unsigned short* XB   = ws16 + XB_OFF;
    const unsigned short* XBb  = XB + (size_t)batch * NN * 64;   // batch slice

    // ---- neighbor element-offsets within batch slice (rows pre-zeroed: no mask) ----
    int voff[KK];
    #pragma unroll
    for (int k = 0; k < KK; ++k) {
        const int idx = __builtin_nontemporal_load(nidx + myrow * KK + k);
        voff[k] = idx * 64 + q * 8;
    }

    // ---- adj row (81 bf16 padded 88) -> 44 dwords in regs (streaming: nt) ----
    unsigned adjw[44];
    {
        const u32x4* ap = (const u32x4*)(Adj + (size_t)myn * 88);
        #pragma unroll
        for (int u = 0; u < 11; ++u) {
            u32x4 w = __builtin_nontemporal_load(ap + u);
            adjw[4 * u + 0] = w.x; adjw[4 * u + 1] = w.y;
            adjw[4 * u + 2] = w.z; adjw[4 * u + 3] = w.w;
        }
    }

    f32x4 acc[4];    // conv accumulators (o-tiles of 16)
    f32x4 acc2[4];   // residual accumulators
    #pragma unroll
    for (int ot = 0; ot < 4; ++ot) { acc[ot] = (f32x4)0.0f; acc2[ot] = (f32x4)0.0f; }

    // ---- 2 f-halves (c) x 9 neighbor slots (t), MFMA K-chunk = 32 ----
    #pragma unroll 1
    for (int c = 0; c < 2; ++c) {
        float v[KK][8];
        #pragma unroll
        for (int k = 0; k < KK; ++k) {
            u16x8 pv = *(const u16x8*)(XBb + voff[k] + c * 32);   // L2-hit gather
            u32x4 pw = __builtin_bit_cast(u32x4, pv);
            v[k][0] = bflo2f(pw.x); v[k][1] = bfhi2f(pw.x);
            v[k][2] = bflo2f(pw.y); v[k][3] = bfhi2f(pw.y);
            v[k][4] = bflo2f(pw.z); v[k][5] = bfhi2f(pw.z);
            v[k][6] = bflo2f(pw.w); v[k][7] = bfhi2f(pw.w);
        }
        #pragma unroll
        for (int t = 0; t < KK; ++t) {
            float m[8] = {0.f,0.f,0.f,0.f,0.f,0.f,0.f,0.f};
            #pragma unroll
            for (int k = 0; k < KK; ++k) {
                const int j = k * 9 + t;                     // compile-time
                unsigned w = adjw[j >> 1];
                float a = (j & 1) ? bfhi2f(w) : bflo2f(w);
                #pragma unroll
                for (int i = 0; i < 8; ++i) m[i] = __builtin_fmaf(a, v[k][i], m[i]);
            }
            u16x8 pk;
            #pragma unroll
            for (int i = 0; i < 8; ++i) pk[i] = f2bf(elu_f(m[i]));
            bf16x8 afrag = __builtin_bit_cast(bf16x8, pk);
            const int mch = c * 9 + t;
            #pragma unroll
            for (int ot = 0; ot < 4; ++ot) {
                const u16x8* wp = (const u16x8*)(Wst + mch * 2048 + (ot * 16 + l15) * 32 + q * 8);
                bf16x8 bfrag = __builtin_bit_cast(bf16x8, *wp);
                acc[ot] = __builtin_amdgcn_mfma_f32_16x16x32_bf16(afrag, bfrag, acc[ot], 0, 0, 0);
            }
        }
    }

    // ---- residual GEMM: xb(row pre-masked) @ mlp_w^T, A-frag direct from XB ----
    #pragma unroll
    for (int c2 = 0; c2 < 2; ++c2) {
        bf16x8 a2 = *(const bf16x8*)(XB + (size_t)myrow * 64 + c2 * 32 + q * 8);
        #pragma unroll
        for (int ot = 0; ot < 4; ++ot) {
            const u16x8* wp = (const u16x8*)(Wst2 + c2 * 2048 + (ot * 16 + l15) * 32 + q * 8);
            bf16x8 b2 = __builtin_bit_cast(bf16x8, *wp);
            acc2[ot] = __builtin_amdgcn_mfma_f32_16x16x32_bf16(a2, b2, acc2[ot], 0, 0, 0);
        }
    }

    // ---- epilogue: elu(conv+cb)*mask + res + mb -> LDS transpose -> 1KB stores ----
    #pragma unroll
    for (int ot = 0; ot < 4; ++ot) {
        const int o = ot * 16 + l15;
        const float cb = conv_b[o];
        const float mb = mlp_b[o];
        #pragma unroll
        for (int i = 0; i < 4; ++i) {
            const int rr = 4 * q + i;                    // C/D: row = 4*(lane>>4)+reg
            float f = elu_f(acc[ot][i] + cb);
            if (n0 + rr == NN - 1) f = 0.0f;             // output mask
            f += acc2[ot][i] + mb;
            sm[wave][rr][o] = f;
        }
    }
    // wave-local LDS readback (no barrier needed), fully-contiguous 1KB stores
    #pragma unroll
    for (int p = 0; p < 4; ++p) {
        const int r = p * 4 + q;
        f32x4 vv = *(const f32x4*)&sm[wave][r][l15 * 4];
        __builtin_nontemporal_store(vv, (f32x4*)(out + (size_t)(rowbase + r) * 64 + l15 * 4));
    }
}

extern "C" void kernel_launch(void* const* d_in, const int* in_sizes, int n_in,
                              void* d_out, int out_size, void* d_ws, size_t ws_size,
                              hipStream_t stream) {
    const float* x      = (const float*)d_in[0];
    const int*   nidx   = (const int*)  d_in[1];
    const float* adj    = (const float*)d_in[2];
    const float* conv_w = (const float*)d_in[3];
    const float* conv_b = (const float*)d_in[4];
    const float* mlp_w  = (const float*)d_in[5];
    const float* mlp_b  = (const float*)d_in[6];
    unsigned short* ws16 = (unsigned short*)d_ws;
    float* out = (float*)d_out;

    const int prep_blocks = (XB_ELE / 8) / 256;           // 5000
    paiconv_prep<<<prep_blocks, 256, 0, stream>>>(x, adj, conv_w, mlp_w, ws16);

    const int main_blocks = 8 * 313;                      // batch-major, XCD-pinned
    paiconv_main<<<main_blocks, 256, 0, stream>>>(nidx, conv_b, mlp_b, ws16, out);
}